// Round 6
// baseline (279.846 us; speedup 1.0000x reference)
//
#include <hip/hip_runtime.h>

#define B_  4
#define C1  256
#define C2  128
#define HH  64
#define WW  64
#define H2  128
#define W2  128

using short8  = __attribute__((ext_vector_type(8))) short;
using floatx4 = __attribute__((ext_vector_type(4))) float;
typedef unsigned short ushort_t;

// ---- workspace layout (bytes) ----
#define W1C_OFF 0u                                   // [cls4][tap4][co128][ci256] bf16
#define W1C_ELEMS (4 * 4 * 128 * 256)
#define W2C_OFF (W1C_ELEMS * 2u)                     // [tap9][o128][ci128] bf16
#define W2C_ELEMS (9 * 128 * 128)
#define KG_OFF  (W2C_OFF + W2C_ELEMS * 2u)           // [b][h][tap9][w128] fp32
#define KG_ELEMS (B_ * H2 * 9 * W2)
#define XT_OFF  (KG_OFF + KG_ELEMS * 4u)             // x -> [b][ih][iw][ci] bf16
#define XT_ELEMS (B_ * HH * WW * C1)
#define Y_OFF   (XT_OFF + XT_ELEMS * 2u)             // y -> [b][h][w][c] bf16
#define Y_ELEMS (B_ * H2 * W2 * C2)

static __device__ __forceinline__ ushort_t f2bf(float f) {
    union { float f; unsigned u; } v; v.f = f;
    unsigned r = v.u + 0x7FFFu + ((v.u >> 16) & 1u);   // RNE
    return (ushort_t)(r >> 16);
}

// ---------------------------------------------------------------------------
// Fused prep: blocks [0,128) = w1c, [128,192) = w2c, [192,448) = xT.
// One launch instead of three (cuts graph-replay gaps).
// ---------------------------------------------------------------------------
__global__ __launch_bounds__(256) void prep_kernel(const float* __restrict__ w1,
                                                   const float* __restrict__ w2,
                                                   const float* __restrict__ x,
                                                   ushort_t* __restrict__ w1c,
                                                   ushort_t* __restrict__ w2c,
                                                   ushort_t* __restrict__ xT) {
    __shared__ float tile[64 * 65];
    const int bid = blockIdx.x;
    const int tid = threadIdx.x;

    if (bid < 128) {
        // ---- w1 -> w1c[cls][tap][co][ci] bf16 (block = co, lanes = ci)
        const int co = bid;
        const int ci = tid;
        float v[16];
#pragma unroll
        for (int q = 0; q < 4; ++q) {
            const float4 f = *reinterpret_cast<const float4*>(&w1[(ci * C2 + co) * 16 + q * 4]);
            v[q * 4 + 0] = f.x; v[q * 4 + 1] = f.y; v[q * 4 + 2] = f.z; v[q * 4 + 3] = f.w;
        }
#pragma unroll
        for (int cls = 0; cls < 4; ++cls)
#pragma unroll
            for (int tap = 0; tap < 4; ++tap) {
                const int kh = (cls >> 1) + 2 * (tap >> 1);
                const int kw = (cls & 1) + 2 * (tap & 1);
                w1c[((cls * 4 + tap) * 128 + co) * 256 + ci] = f2bf(v[kh * 4 + kw]);
            }
    } else if (bid < 192) {
        // ---- w2 -> w2c[tap][o][ci] bf16, flip baked (block = 2 o's, lanes = ci)
        const int o  = (bid - 128) * 2 + (tid >> 7);
        const int ci = tid & 127;
        float v[9];
#pragma unroll
        for (int t = 0; t < 9; ++t) v[t] = w2[(ci * C2 + o) * 9 + t];
#pragma unroll
        for (int tap = 0; tap < 9; ++tap) {
            const int fi = 2 - tap / 3;
            const int fj = 2 - tap % 3;
            w2c[((size_t)tap * 128 + o) * 128 + ci] = f2bf(v[fi * 3 + fj]);
        }
    } else {
        // ---- x NCHW fp32 -> xT[b][ih][iw][ci] bf16 (LDS transpose, stride 65)
        const int ih = (bid - 192) & 63;
        const int b  = (bid - 192) >> 6;
        for (int chunk = 0; chunk < 4; ++chunk) {
            const int ci0 = chunk * 64;
            if (chunk) __syncthreads();
#pragma unroll
            for (int it = 0; it < 16; ++it) {
                const int cc = it * 4 + (tid >> 6);
                const int iw = tid & 63;
                tile[iw * 65 + cc] = x[(((size_t)b * C1 + ci0 + cc) * HH + ih) * WW + iw];
            }
            __syncthreads();
#pragma unroll
            for (int it = 0; it < 2; ++it) {
                const int i  = it * 256 + tid;
                const int iw = i >> 3;
                const int t  = i & 7;
                ushort_t pk[8];
#pragma unroll
                for (int j = 0; j < 8; ++j) pk[j] = f2bf(tile[iw * 65 + t * 8 + j]);
                *reinterpret_cast<int4*>(&xT[(((size_t)(b * HH + ih) * WW) + iw) * C1 + ci0 + t * 8]) =
                    *reinterpret_cast<const int4*>(pk);
            }
        }
    }
}

// ---------------------------------------------------------------------------
// k-kernel: kg[b][h][tap][w], 512 threads = 4 c-quarters x 128 w, LDS-reduced.
// ---------------------------------------------------------------------------
__global__ __launch_bounds__(512) void k_kernel(const float* __restrict__ guide,
                                                float* __restrict__ kg) {
    const int h = blockIdx.x;
    const int b = blockIdx.y;
    const int tid = threadIdx.x;
    const int cq  = tid >> 7;
    const int n   = tid & 127;

    float acc[9];
#pragma unroll
    for (int t = 0; t < 9; ++t) acc[t] = 0.f;

    const float* gb = guide + (size_t)b * C2 * H2 * W2;
    for (int c = cq * 32; c < cq * 32 + 32; ++c) {
        const float* grow = gb + (c * H2 + h) * W2;
        const float gc = grow[n];
#pragma unroll
        for (int di = 0; di < 3; ++di) {
            const int hh = h + di - 1;
            const bool rv = (hh >= 0) && (hh < H2);
            const float* gr = gb + (c * H2 + (rv ? hh : 0)) * W2;
#pragma unroll
            for (int dj = 0; dj < 3; ++dj) {
                const int col = n + dj - 1;
                const bool cv = rv && (col >= 0) && (col < W2);
                const float gn = cv ? gr[col] : 0.f;
                const float d = gn - gc;
                acc[di * 3 + dj] += d * d;
            }
        }
    }

    __shared__ float part[4][9][128];
#pragma unroll
    for (int t = 0; t < 9; ++t) part[cq][t][n] = acc[t];
    __syncthreads();

    for (int i = tid; i < 1152; i += 512) {
        const int t  = i >> 7;
        const int nn = i & 127;
        const float s = part[0][t][nn] + part[1][t][nn] + part[2][t][nn] + part[3][t][nn];
        kg[(size_t)(b * H2 + h) * 1152 + i] = __expf(-0.5f * s);
    }
}

// ---------------------------------------------------------------------------
// Deconv MFMA v4: tile 128co x 64pix (one output row), 1024 blocks (4/CU).
// Tap-outer, K=256 B-slab per tap (4 rounds of 64 MFMA/wave). A direct
// global->VGPR (small per-step footprint -> compiler can pipeline).
// ---------------------------------------------------------------------------
__global__ __launch_bounds__(256, 4) void deconv_mfma(const ushort_t* __restrict__ xT,
                                                      const ushort_t* __restrict__ w1c,
                                                      const float* __restrict__ b1,
                                                      ushort_t* __restrict__ y) {
    const int pwc = blockIdx.x;                 // ow parity
    const int oh  = blockIdx.y;
    const int b   = blockIdx.z;
    const int p    = (oh + 1) & 1;              // kh parity
    const int ihA  = (oh + 1 - p) >> 1;
    const int pwp  = 1 - pwc;                   // kw parity
    const int cls  = p * 2 + pwp;

    const int tid  = threadIdx.x;
    const int lane = tid & 63;
    const int wave = tid >> 6;
    const int wm   = (wave & 1) * 64;
    const int wn   = (wave >> 1) * 32;
    const int quad = lane >> 4;
    const int l15  = lane & 15;

    __shared__ __align__(16) ushort_t lds[64 * 264];   // Bs [n64][ci], stride 264; reused as Ot

    floatx4 acc[4][2];
#pragma unroll
    for (int mi = 0; mi < 4; ++mi)
#pragma unroll
        for (int ni = 0; ni < 2; ++ni) acc[mi][ni] = (floatx4)0.f;

    for (int tap = 0; tap < 4; ++tap) {
        const int th = tap >> 1, tw = tap & 1;
        __syncthreads();
        // ---- stage B: 64 rows x 32 int4 = 2048 int4 (8/thread)
#pragma unroll
        for (int it = 0; it < 8; ++it) {
            const int i   = it * 256 + tid;
            const int row = i >> 5;
            const int t   = i & 31;
            const int ih  = ihA - th;
            const int iw  = row + pwc - tw;
            int4 v = make_int4(0, 0, 0, 0);
            if (ih >= 0 && ih < HH && iw >= 0 && iw < WW)
                v = *reinterpret_cast<const int4*>(
                    &xT[(((size_t)(b * HH + ih) * WW) + iw) * C1 + t * 8]);
            *reinterpret_cast<int4*>(&lds[row * 264 + t * 8]) = v;
        }
        __syncthreads();

        const ushort_t* wsrc = w1c + (size_t)(cls * 4 + tap) * 128 * 256;
#pragma unroll
        for (int ks = 0; ks < 8; ++ks) {
            const int ko = ks * 32 + quad * 8;
            short8 af[4], bfr[2];
#pragma unroll
            for (int mi = 0; mi < 4; ++mi)
                af[mi] = *reinterpret_cast<const short8*>(
                    &wsrc[(wm + mi * 16 + l15) * 256 + ko]);
#pragma unroll
            for (int ni = 0; ni < 2; ++ni)
                bfr[ni] = *reinterpret_cast<const short8*>(
                    &lds[(wn + ni * 16 + l15) * 264 + ko]);
#pragma unroll
            for (int mi = 0; mi < 4; ++mi)
#pragma unroll
                for (int ni = 0; ni < 2; ++ni)
                    acc[mi][ni] = __builtin_amdgcn_mfma_f32_16x16x32_bf16(
                        af[mi], bfr[ni], acc[mi][ni], 0, 0, 0);
        }
    }

    // ---- epilogue: LDS transpose -> y[b][oh][ow][co] bf16
    __syncthreads();
    ushort_t* Ot = lds;                      // [n64][co], stride 136
#pragma unroll
    for (int mi = 0; mi < 4; ++mi)
#pragma unroll
        for (int ni = 0; ni < 2; ++ni) {
            const int n = wn + ni * 16 + l15;
#pragma unroll
            for (int r = 0; r < 4; ++r) {
                const int co = wm + mi * 16 + quad * 4 + r;
                Ot[n * 136 + co] = f2bf(acc[mi][ni][r] + b1[co]);
            }
        }
    __syncthreads();
#pragma unroll
    for (int it = 0; it < 4; ++it) {
        const int i   = it * 256 + tid;
        const int n   = i >> 4;
        const int t   = i & 15;
        const int ow  = 2 * n + pwc;
        const int4 v = *reinterpret_cast<const int4*>(&Ot[n * 136 + t * 8]);
        *reinterpret_cast<int4*>(&y[(((size_t)(b * H2 + oh) * W2) + ow) * C2 + t * 8]) = v;
    }
}

// ---------------------------------------------------------------------------
// PAC MFMA v4: tile 128o x 64w, 1024 blocks (4/CU). Y-slab 66 cols per di
// (3 stagings, reused by 3 taps); A direct global->VGPR; k-scale in register
// epilogue per tap.
// ---------------------------------------------------------------------------
__global__ __launch_bounds__(256, 4) void pac_mfma(const ushort_t* __restrict__ y,
                                                   const float* __restrict__ kg,
                                                   const ushort_t* __restrict__ w2c,
                                                   const float* __restrict__ b2,
                                                   float* __restrict__ out) {
    const int w0 = blockIdx.x * 64;
    const int h  = blockIdx.y;
    const int b  = blockIdx.z;

    const int tid  = threadIdx.x;
    const int lane = tid & 63;
    const int wave = tid >> 6;
    const int wm   = (wave & 1) * 64;
    const int wn   = (wave >> 1) * 32;
    const int quad = lane >> 4;
    const int l15  = lane & 15;

    __shared__ __align__(16) ushort_t Ys[66 * 136];   // cols w0-1..w0+64
    __shared__ float k_lds[9 * 64];

#pragma unroll
    for (int it = 0; it < 3; ++it) {
        const int i = it * 256 + tid;
        if (i < 576) {
            const int tap = i >> 6;
            const int wl  = i & 63;
            k_lds[i] = kg[(size_t)(b * H2 + h) * 1152 + tap * 128 + w0 + wl];
        }
    }

    float out_acc[4][2][4];
#pragma unroll
    for (int mi = 0; mi < 4; ++mi)
#pragma unroll
        for (int ni = 0; ni < 2; ++ni)
#pragma unroll
            for (int r = 0; r < 4; ++r) out_acc[mi][ni][r] = 0.f;

    for (int di = 0; di < 3; ++di) {
        const int hh = h + di - 1;
        if (hh < 0 || hh >= H2) continue;              // block-uniform
        __syncthreads();
        // ---- stage Y slab: 66 rows (cols w0-1..w0+64) x 16 int4
#pragma unroll
        for (int it = 0; it < 5; ++it) {
            const int i = it * 256 + tid;
            if (i < 1056) {
                const int r   = i >> 4;
                const int t   = i & 15;
                const int col = w0 - 1 + r;
                int4 v = make_int4(0, 0, 0, 0);
                if (col >= 0 && col < W2)
                    v = *reinterpret_cast<const int4*>(
                        &y[(((size_t)(b * H2 + hh) * W2) + col) * C2 + t * 8]);
                *reinterpret_cast<int4*>(&Ys[r * 136 + t * 8]) = v;
            }
        }
        __syncthreads();

        for (int dj = 0; dj < 3; ++dj) {
            const int tap = di * 3 + dj;
            const ushort_t* wsrc = w2c + (size_t)tap * 128 * 128;

            floatx4 acc[4][2];
#pragma unroll
            for (int mi = 0; mi < 4; ++mi)
#pragma unroll
                for (int ni = 0; ni < 2; ++ni) acc[mi][ni] = (floatx4)0.f;

#pragma unroll
            for (int ks = 0; ks < 4; ++ks) {
                const int ko = ks * 32 + quad * 8;
                short8 af[4], bfr[2];
#pragma unroll
                for (int mi = 0; mi < 4; ++mi)
                    af[mi] = *reinterpret_cast<const short8*>(
                        &wsrc[(wm + mi * 16 + l15) * 128 + ko]);
#pragma unroll
                for (int ni = 0; ni < 2; ++ni)
                    bfr[ni] = *reinterpret_cast<const short8*>(
                        &Ys[(wn + ni * 16 + l15 + dj) * 136 + ko]);
#pragma unroll
                for (int mi = 0; mi < 4; ++mi)
#pragma unroll
                    for (int ni = 0; ni < 2; ++ni)
                        acc[mi][ni] = __builtin_amdgcn_mfma_f32_16x16x32_bf16(
                            af[mi], bfr[ni], acc[mi][ni], 0, 0, 0);
            }
            // ---- scale by k_tap[w], accumulate
            float kv[2];
#pragma unroll
            for (int ni = 0; ni < 2; ++ni)
                kv[ni] = k_lds[tap * 64 + wn + ni * 16 + l15];
#pragma unroll
            for (int mi = 0; mi < 4; ++mi)
#pragma unroll
                for (int ni = 0; ni < 2; ++ni)
#pragma unroll
                    for (int r = 0; r < 4; ++r)
                        out_acc[mi][ni][r] += kv[ni] * acc[mi][ni][r];
        }
    }

    // ---- final store: out NCHW fp32
#pragma unroll
    for (int mi = 0; mi < 4; ++mi)
#pragma unroll
        for (int ni = 0; ni < 2; ++ni) {
            const int w = w0 + wn + ni * 16 + l15;
#pragma unroll
            for (int r = 0; r < 4; ++r) {
                const int o = wm + mi * 16 + quad * 4 + r;
                out[(((size_t)b * C2 + o) * H2 + h) * W2 + w] = out_acc[mi][ni][r] + b2[o];
            }
        }
}

extern "C" void kernel_launch(void* const* d_in, const int* in_sizes, int n_in,
                              void* d_out, int out_size, void* d_ws, size_t ws_size,
                              hipStream_t stream) {
    const float* x     = (const float*)d_in[0];
    const float* guide = (const float*)d_in[1];
    const float* w1    = (const float*)d_in[2];
    const float* b1    = (const float*)d_in[3];
    const float* w2    = (const float*)d_in[4];
    const float* b2    = (const float*)d_in[5];
    float* out = (float*)d_out;

    ushort_t* w1c = (ushort_t*)((char*)d_ws + W1C_OFF);
    ushort_t* w2c = (ushort_t*)((char*)d_ws + W2C_OFF);
    float*    kg  = (float*)((char*)d_ws + KG_OFF);
    ushort_t* xT  = (ushort_t*)((char*)d_ws + XT_OFF);
    ushort_t* y   = (ushort_t*)((char*)d_ws + Y_OFF);

    prep_kernel<<<448, 256, 0, stream>>>(w1, w2, x, w1c, w2c, xT);
    k_kernel<<<dim3(H2, B_), 512, 0, stream>>>(guide, kg);
    deconv_mfma<<<dim3(2, H2, B_), 256, 0, stream>>>(xT, w1c, b1, y);
    pac_mfma<<<dim3(2, H2, B_), 256, 0, stream>>>(y, kg, w2c, b2, out);
}

// Round 7
// 227.071 us; speedup vs baseline: 1.2324x; 1.2324x over previous
//
#include <hip/hip_runtime.h>

#define B_  4
#define C1  256
#define C2  128
#define HH  64
#define WW  64
#define H2  128
#define W2  128

using short8  = __attribute__((ext_vector_type(8))) short;
using floatx4 = __attribute__((ext_vector_type(4))) float;
typedef unsigned short ushort_t;

// ---- workspace layout (bytes) ----
#define W1C_OFF 0u                                   // [cls4][tap4][co128][ci256] bf16
#define W1C_ELEMS (4 * 4 * 128 * 256)
#define W2C_OFF (W1C_ELEMS * 2u)                     // [tap9][o128][ci128] bf16
#define W2C_ELEMS (9 * 128 * 128)
#define KG_OFF  (W2C_OFF + W2C_ELEMS * 2u)           // [b][h][tap9][w128] fp32
#define KG_ELEMS (B_ * H2 * 9 * W2)
#define XT_OFF  (KG_OFF + KG_ELEMS * 4u)             // x -> [b][ih][iw][ci] bf16
#define XT_ELEMS (B_ * HH * WW * C1)
#define Y_OFF   (XT_OFF + XT_ELEMS * 2u)             // y -> [b][h][w][c] bf16
#define Y_ELEMS (B_ * H2 * W2 * C2)

static __device__ __forceinline__ ushort_t f2bf(float f) {
    union { float f; unsigned u; } v; v.f = f;
    unsigned r = v.u + 0x7FFFu + ((v.u >> 16) & 1u);   // RNE
    return (ushort_t)(r >> 16);
}

// ---------------------------------------------------------------------------
// Launch 1 — fused prep: blocks [0,128)=w1c, [128,192)=w2c, [192,448)=xT.
// (proven in R6)
// ---------------------------------------------------------------------------
__global__ __launch_bounds__(256) void prep_kernel(const float* __restrict__ w1,
                                                   const float* __restrict__ w2,
                                                   const float* __restrict__ x,
                                                   ushort_t* __restrict__ w1c,
                                                   ushort_t* __restrict__ w2c,
                                                   ushort_t* __restrict__ xT) {
    __shared__ float tile[64 * 65];
    const int bid = blockIdx.x;
    const int tid = threadIdx.x;

    if (bid < 128) {
        const int co = bid;
        const int ci = tid;
        float v[16];
#pragma unroll
        for (int q = 0; q < 4; ++q) {
            const float4 f = *reinterpret_cast<const float4*>(&w1[(ci * C2 + co) * 16 + q * 4]);
            v[q * 4 + 0] = f.x; v[q * 4 + 1] = f.y; v[q * 4 + 2] = f.z; v[q * 4 + 3] = f.w;
        }
#pragma unroll
        for (int cls = 0; cls < 4; ++cls)
#pragma unroll
            for (int tap = 0; tap < 4; ++tap) {
                const int kh = (cls >> 1) + 2 * (tap >> 1);
                const int kw = (cls & 1) + 2 * (tap & 1);
                w1c[((cls * 4 + tap) * 128 + co) * 256 + ci] = f2bf(v[kh * 4 + kw]);
            }
    } else if (bid < 192) {
        const int o  = (bid - 128) * 2 + (tid >> 7);
        const int ci = tid & 127;
        float v[9];
#pragma unroll
        for (int t = 0; t < 9; ++t) v[t] = w2[(ci * C2 + o) * 9 + t];
#pragma unroll
        for (int tap = 0; tap < 9; ++tap) {
            const int fi = 2 - tap / 3;
            const int fj = 2 - tap % 3;
            w2c[((size_t)tap * 128 + o) * 128 + ci] = f2bf(v[fi * 3 + fj]);
        }
    } else {
        const int ih = (bid - 192) & 63;
        const int b  = (bid - 192) >> 6;
        for (int chunk = 0; chunk < 4; ++chunk) {
            const int ci0 = chunk * 64;
            if (chunk) __syncthreads();
#pragma unroll
            for (int it = 0; it < 16; ++it) {
                const int cc = it * 4 + (tid >> 6);
                const int iw = tid & 63;
                tile[iw * 65 + cc] = x[(((size_t)b * C1 + ci0 + cc) * HH + ih) * WW + iw];
            }
            __syncthreads();
#pragma unroll
            for (int it = 0; it < 2; ++it) {
                const int i  = it * 256 + tid;
                const int iw = i >> 3;
                const int t  = i & 7;
                ushort_t pk[8];
#pragma unroll
                for (int j = 0; j < 8; ++j) pk[j] = f2bf(tile[iw * 65 + t * 8 + j]);
                *reinterpret_cast<int4*>(&xT[(((size_t)(b * HH + ih) * WW) + iw) * C1 + ci0 + t * 8]) =
                    *reinterpret_cast<const int4*>(pk);
            }
        }
    }
}

// ---------------------------------------------------------------------------
// Launch 2 — fused deconv (blocks 0..511, R5 structure: best measured 57 us)
//            + k-kernel (blocks 512..1535, 256-thread variant, 64 w per block).
// Independent work co-scheduled: k's VALU waves fill CUs while deconv blocks
// sit at staging barriers.
// ---------------------------------------------------------------------------
__global__ __launch_bounds__(256, 2) void deconv_k_fused(const ushort_t* __restrict__ xT,
                                                         const ushort_t* __restrict__ w1c,
                                                         const float* __restrict__ b1,
                                                         ushort_t* __restrict__ y,
                                                         const float* __restrict__ guide,
                                                         float* __restrict__ kg) {
    __shared__ __align__(16) char smem[128 * 264 * 2];   // 67.6 KB
    const int bid = blockIdx.x;
    const int tid = threadIdx.x;

    if (bid < 512) {
        // ================= deconv (R5 structure, verbatim) =================
        const int pwc = bid & 1;
        const int pr  = (bid >> 1) & 63;
        const int b   = bid >> 7;
        const int base_oh = (pr >> 1) * 4 + (pr & 1);
        const int p    = (base_oh + 1) & 1;
        const int ihA0 = (base_oh + 1 - p) >> 1;
        const int pwp  = 1 - pwc;
        const int cls  = p * 2 + pwp;

        const int lane = tid & 63;
        const int wave = tid >> 6;
        const int wm   = (wave & 1) * 64;
        const int wn   = (wave >> 1) * 64;
        const int quad = lane >> 4;
        const int l15  = lane & 15;

        ushort_t* lds = (ushort_t*)smem;                 // Bs [128][264]; reused as Ot

        floatx4 acc[4][4];
#pragma unroll
        for (int mi = 0; mi < 4; ++mi)
#pragma unroll
            for (int ni = 0; ni < 4; ++ni) acc[mi][ni] = (floatx4)0.f;

        for (int tap = 0; tap < 4; ++tap) {
            const int th = tap >> 1, tw = tap & 1;
            __syncthreads();
#pragma unroll
            for (int it = 0; it < 16; ++it) {
                const int i   = it * 256 + tid;
                const int row = i >> 5;
                const int t   = i & 31;
                const int rh  = row >> 6;
                const int n64 = row & 63;
                const int ih  = ihA0 + rh - th;
                const int iw  = n64 + pwc - tw;
                int4 v = make_int4(0, 0, 0, 0);
                if (ih >= 0 && ih < HH && iw >= 0 && iw < WW)
                    v = *reinterpret_cast<const int4*>(
                        &xT[(((size_t)(b * HH + ih) * WW) + iw) * C1 + t * 8]);
                *reinterpret_cast<int4*>(&lds[row * 264 + t * 8]) = v;
            }
            __syncthreads();

            const ushort_t* wsrc = w1c + (size_t)(cls * 4 + tap) * 128 * 256;
#pragma unroll
            for (int kc = 0; kc < 4; ++kc) {
#pragma unroll
                for (int k2 = 0; k2 < 2; ++k2) {
                    const int ko = kc * 64 + k2 * 32 + quad * 8;
                    short8 af[4], bfr[4];
#pragma unroll
                    for (int mi = 0; mi < 4; ++mi)
                        af[mi] = *reinterpret_cast<const short8*>(
                            &wsrc[(wm + mi * 16 + l15) * 256 + ko]);
#pragma unroll
                    for (int ni = 0; ni < 4; ++ni)
                        bfr[ni] = *reinterpret_cast<const short8*>(
                            &lds[(wn + ni * 16 + l15) * 264 + ko]);
#pragma unroll
                    for (int mi = 0; mi < 4; ++mi)
#pragma unroll
                        for (int ni = 0; ni < 4; ++ni)
                            acc[mi][ni] = __builtin_amdgcn_mfma_f32_16x16x32_bf16(
                                af[mi], bfr[ni], acc[mi][ni], 0, 0, 0);
                }
            }
        }

        __syncthreads();
        ushort_t* Ot = (ushort_t*)smem;                  // [n][co], stride 136
#pragma unroll
        for (int mi = 0; mi < 4; ++mi)
#pragma unroll
            for (int ni = 0; ni < 4; ++ni) {
                const int n = wn + ni * 16 + l15;
#pragma unroll
                for (int r = 0; r < 4; ++r) {
                    const int co = wm + mi * 16 + quad * 4 + r;
                    Ot[n * 136 + co] = f2bf(acc[mi][ni][r] + b1[co]);
                }
            }
        __syncthreads();
#pragma unroll
        for (int it = 0; it < 8; ++it) {
            const int i   = it * 256 + tid;
            const int n   = i >> 4;
            const int t   = i & 15;
            const int rh  = n >> 6;
            const int n64 = n & 63;
            const int oh  = base_oh + 2 * rh;
            const int ow  = 2 * n64 + pwc;
            const int4 v = *reinterpret_cast<const int4*>(&Ot[n * 136 + t * 8]);
            *reinterpret_cast<int4*>(&y[(((size_t)(b * H2 + oh) * W2) + ow) * C2 + t * 8]) = v;
        }
    } else {
        // ================= k-kernel (256 threads, 64 w per block) ==========
        const int kid = bid - 512;               // 0..1023
        const int w0  = (kid & 1) * 64;
        const int h   = (kid >> 1) & 127;
        const int b   = kid >> 8;
        const int cq  = tid >> 6;                // 0..3
        const int nl  = tid & 63;
        const int n   = w0 + nl;

        float acc[9];
#pragma unroll
        for (int t = 0; t < 9; ++t) acc[t] = 0.f;

        const float* gb = guide + (size_t)b * C2 * H2 * W2;
        for (int c = cq * 32; c < cq * 32 + 32; ++c) {
            const float gc = gb[(c * H2 + h) * W2 + n];
#pragma unroll
            for (int di = 0; di < 3; ++di) {
                const int hh = h + di - 1;
                const bool rv = (hh >= 0) && (hh < H2);
                const float* gr = gb + (c * H2 + (rv ? hh : 0)) * W2;
#pragma unroll
                for (int dj = 0; dj < 3; ++dj) {
                    const int col = n + dj - 1;
                    const bool cv = rv && (col >= 0) && (col < W2);
                    const float gn = cv ? gr[col] : 0.f;
                    const float d = gn - gc;
                    acc[di * 3 + dj] += d * d;
                }
            }
        }

        float* part = (float*)smem;              // [4][9][64] = 9.2 KB
#pragma unroll
        for (int t = 0; t < 9; ++t) part[(cq * 9 + t) * 64 + nl] = acc[t];
        __syncthreads();

        for (int i = tid; i < 576; i += 256) {   // 9 taps x 64 w
            const int t  = i >> 6;
            const int nn = i & 63;
            const float s = part[t * 64 + nn] + part[(9 + t) * 64 + nn] +
                            part[(18 + t) * 64 + nn] + part[(27 + t) * 64 + nn];
            kg[(size_t)(b * H2 + h) * 1152 + t * 128 + w0 + nn] = __expf(-0.5f * s);
        }
    }
}

// ---------------------------------------------------------------------------
// Launch 3 — PAC MFMA (R4 structure verbatim: best measured 45 us).
// ---------------------------------------------------------------------------
__global__ __launch_bounds__(256, 2) void pac_mfma(const ushort_t* __restrict__ y,
                                                   const float* __restrict__ kg,
                                                   const ushort_t* __restrict__ w2c,
                                                   const float* __restrict__ b2,
                                                   float* __restrict__ out) {
    const int h = blockIdx.x;
    const int b = blockIdx.y;

    const int tid  = threadIdx.x;
    const int lane = tid & 63;
    const int wave = tid >> 6;
    const int wm   = (wave & 1) * 64;
    const int wn   = (wave >> 1) * 64;
    const int quad = lane >> 4;
    const int l15  = lane & 15;

    __shared__ __align__(16) ushort_t As[128 * 136];
    __shared__ __align__(16) ushort_t Ys[130 * 136];
    __shared__ float k_lds[9 * 128];

    for (int i = tid; i < 1152; i += 256)
        k_lds[i] = kg[(size_t)(b * H2 + h) * 1152 + i];

    float out_acc[4][4][4];
#pragma unroll
    for (int mi = 0; mi < 4; ++mi)
#pragma unroll
        for (int ni = 0; ni < 4; ++ni)
#pragma unroll
            for (int r = 0; r < 4; ++r) out_acc[mi][ni][r] = 0.f;

    for (int di = 0; di < 3; ++di) {
        const int hh = h + di - 1;
        if (hh < 0 || hh >= H2) continue;              // block-uniform
        __syncthreads();
#pragma unroll
        for (int it = 0; it < 8; ++it) {
            const int i  = it * 256 + tid;
            const int r  = i >> 4;
            const int t  = i & 15;
            const int4 v = *reinterpret_cast<const int4*>(
                &y[(((size_t)(b * H2 + hh) * W2) + r) * C2 + t * 8]);
            *reinterpret_cast<int4*>(&Ys[(r + 1) * 136 + t * 8]) = v;
        }
        if (tid < 32) {
            const int ra = (tid < 16) ? 0 : 129;
            const int t  = tid & 15;
            *reinterpret_cast<int4*>(&Ys[ra * 136 + t * 8]) = make_int4(0, 0, 0, 0);
        }

        for (int dj = 0; dj < 3; ++dj) {
            const int tap = di * 3 + dj;
            __syncthreads();
#pragma unroll
            for (int it = 0; it < 8; ++it) {
                const int i   = it * 256 + tid;
                const int row = i >> 4;
                const int t   = i & 15;
                const int4 v = *reinterpret_cast<const int4*>(
                    &w2c[((size_t)tap * 128 + row) * 128 + t * 8]);
                *reinterpret_cast<int4*>(&As[row * 136 + t * 8]) = v;
            }
            __syncthreads();

            floatx4 acc[4][4];
#pragma unroll
            for (int mi = 0; mi < 4; ++mi)
#pragma unroll
                for (int ni = 0; ni < 4; ++ni) acc[mi][ni] = (floatx4)0.f;

#pragma unroll
            for (int kc = 0; kc < 4; ++kc) {
                short8 af[4], bfr[4];
#pragma unroll
                for (int mi = 0; mi < 4; ++mi)
                    af[mi] = *reinterpret_cast<const short8*>(
                        &As[(wm + mi * 16 + l15) * 136 + kc * 32 + quad * 8]);
#pragma unroll
                for (int ni = 0; ni < 4; ++ni)
                    bfr[ni] = *reinterpret_cast<const short8*>(
                        &Ys[(wn + ni * 16 + l15 + dj) * 136 + kc * 32 + quad * 8]);
#pragma unroll
                for (int mi = 0; mi < 4; ++mi)
#pragma unroll
                    for (int ni = 0; ni < 4; ++ni)
                        acc[mi][ni] = __builtin_amdgcn_mfma_f32_16x16x32_bf16(
                            af[mi], bfr[ni], acc[mi][ni], 0, 0, 0);
            }
            float kv[4];
#pragma unroll
            for (int ni = 0; ni < 4; ++ni)
                kv[ni] = k_lds[tap * 128 + wn + ni * 16 + l15];
#pragma unroll
            for (int mi = 0; mi < 4; ++mi)
#pragma unroll
                for (int ni = 0; ni < 4; ++ni)
#pragma unroll
                    for (int r = 0; r < 4; ++r)
                        out_acc[mi][ni][r] += kv[ni] * acc[mi][ni][r];
        }
    }

#pragma unroll
    for (int mi = 0; mi < 4; ++mi)
#pragma unroll
        for (int ni = 0; ni < 4; ++ni) {
            const int w = wn + ni * 16 + l15;
#pragma unroll
            for (int r = 0; r < 4; ++r) {
                const int o = wm + mi * 16 + quad * 4 + r;
                out[(((size_t)b * C2 + o) * H2 + h) * W2 + w] = out_acc[mi][ni][r] + b2[o];
            }
        }
}

extern "C" void kernel_launch(void* const* d_in, const int* in_sizes, int n_in,
                              void* d_out, int out_size, void* d_ws, size_t ws_size,
                              hipStream_t stream) {
    const float* x     = (const float*)d_in[0];
    const float* guide = (const float*)d_in[1];
    const float* w1    = (const float*)d_in[2];
    const float* b1    = (const float*)d_in[3];
    const float* w2    = (const float*)d_in[4];
    const float* b2    = (const float*)d_in[5];
    float* out = (float*)d_out;

    ushort_t* w1c = (ushort_t*)((char*)d_ws + W1C_OFF);
    ushort_t* w2c = (ushort_t*)((char*)d_ws + W2C_OFF);
    float*    kg  = (float*)((char*)d_ws + KG_OFF);
    ushort_t* xT  = (ushort_t*)((char*)d_ws + XT_OFF);
    ushort_t* y   = (ushort_t*)((char*)d_ws + Y_OFF);

    prep_kernel<<<448, 256, 0, stream>>>(w1, w2, x, w1c, w2c, xT);
    deconv_k_fused<<<1536, 256, 0, stream>>>(xT, w1c, b1, y, guide, kg);
    pac_mfma<<<dim3(H2, B_), 256, 0, stream>>>(y, kg, w2c, b2, out);
}